// Round 7
// baseline (666.687 us; speedup 1.0000x reference)
//
#include <hip/hip_runtime.h>
#include <hip/hip_bf16.h>
#include <math.h>

#define NCH 64       // C
#define T_LEN 65536
#define NLAYER 18

typedef __attribute__((ext_vector_type(8))) short bf16x8;   // 8 bf16 = 4 VGPRs
typedef __attribute__((ext_vector_type(4))) short bf16x4;   // 4 bf16 = 2 VGPRs
typedef __attribute__((ext_vector_type(4))) float f32x4;

static __device__ __forceinline__ float bf2f(short s) {
    union { short u[2]; float f; } v;
    v.u[0] = 0; v.u[1] = s;
    return v.f;
}
static __device__ __forceinline__ short f2bf(float f) {
    __hip_bfloat16 h = __float2bfloat16(f);
    return *(short*)&h;
}
// gated = tanh(x)*sigmoid(y) = (e^{2x}-1) / ((e^{2x}+1)(1+e^{-y}))
// 2 exp + 1 rcp. x clamped to +-15 so num stays finite; den=inf -> rcp=0 ok.
static __device__ __forceinline__ float gate_fn(float x, float y) {
    x = fminf(fmaxf(x, -15.f), 15.f);
    float e2 = __expf(2.f * x);
    float em = __expf(-y);
    return (e2 - 1.f) * __builtin_amdgcn_rcpf((e2 + 1.f) * (1.f + em));
}
// XOR-swizzled LDS index for pitch-64 bf16 rows (128 B = 8 chunks of 16 B).
// Keeps 16B chunks intact; spreads row starts over all banks. Bijective per
// row; every access site (read & write) goes through sw() -> consistent.
static __device__ __forceinline__ int sw(int row, int elem) {
    return (row << 6) + ((((elem >> 3) ^ (row & 7)) << 3) | (elem & 7));
}

// ---------------------------------------------------------------------------
// whid[l][o][k]: k<64 -> hid_w[l][o][k][0] (past tap), k>=64 -> [k-64][1] (cur)
// ---------------------------------------------------------------------------
__global__ void convert_weights_kernel(const float* __restrict__ hid_w,
                                       const float* __restrict__ res_w,
                                       __hip_bfloat16* __restrict__ whid,
                                       __hip_bfloat16* __restrict__ wres) {
    int gid = blockIdx.x * 256 + threadIdx.x;
    if (gid < NLAYER * 128 * 128) {
        int l   = gid >> 14;
        int rem = gid & 16383;
        int o   = rem >> 7;
        int k   = rem & 127;
        float v = (k < 64)
            ? hid_w[((l * 128 + o) * 64 + k) * 2]
            : hid_w[((l * 128 + o) * 64 + (k - 64)) * 2 + 1];
        whid[gid] = __float2bfloat16(v);
    }
    if (gid < NLAYER * 64 * 64) {
        wres[gid] = __float2bfloat16(res_w[gid]);
    }
}

// ---------------------------------------------------------------------------
// Fused 6-layer pass (dilations 1,2,4,8,16,32; halo sum = 63).
// Window [t0-64, t0+128): 64 halo + 128 output. A = residual stream in-place,
// G = gated. Pitch-64 + xor-swizzle -> 48 KB LDS -> 3 blocks/CU.
// Skip->mix: R5-proven scalar reduction from G (via sw()), accumulated in
// registers across all 6 layers, one acc RMW at the end.
// ---------------------------------------------------------------------------
__global__ __launch_bounds__(256, 3) void fused6_kernel(
    const void* __restrict__ src,                 // fp32 x | bf16 prev
    __hip_bfloat16* __restrict__ next,            // [B][T][C]
    float* __restrict__ acc,                      // [B][T]
    const __hip_bfloat16* __restrict__ whid_all,  // [18][128][128]
    const float* __restrict__ hb_all,             // [18][128]
    const __hip_bfloat16* __restrict__ wres_all,  // [18][64][64]
    const float* __restrict__ rb_all,             // [18][64]
    const float* __restrict__ mix_w,              // [1152]
    const float* __restrict__ in_w,               // [64]
    const float* __restrict__ in_b,               // [64]
    int lbase, int is_first) {
    __shared__ __align__(16) __hip_bfloat16 A[192 * 64];
    __shared__ __align__(16) __hip_bfloat16 G[192 * 64];

    const int b    = blockIdx.x >> 9;          // 512 windows per batch
    const int widx = blockIdx.x & 511;
    const int t0   = widx << 7;
    const int tw   = t0 - 64;

    const int tid  = threadIdx.x;
    const int lane = tid & 63;
    const int w4   = tid >> 6;
    const int l15  = lane & 15;
    const int quad = lane >> 4;
    const int m0   = w4 * 16;
    const int rr   = tid >> 3;                 // 0..31
    const int co   = (tid & 7) * 8;

    // ---- stage input window [tw, tw+192) ----
    if (is_first) {
        const float* x = (const float*)src;
        float iw[8], ib[8];
#pragma unroll
        for (int j = 0; j < 8; ++j) { iw[j] = in_w[co + j]; ib[j] = in_b[co + j]; }
#pragma unroll
        for (int round = 0; round < 6; ++round) {
            int r  = round * 32 + rr;
            int gt = tw + r;
            bf16x8 v = {0, 0, 0, 0, 0, 0, 0, 0};
            if (gt >= 0) {
                float xv = x[(size_t)b * T_LEN + gt];
#pragma unroll
                for (int j = 0; j < 8; ++j) v[j] = f2bf(iw[j] * xv + ib[j]);
            }
            *(bf16x8*)(&A[sw(r, co)]) = v;
        }
    } else {
        const __hip_bfloat16* prev = (const __hip_bfloat16*)src;
#pragma unroll
        for (int round = 0; round < 6; ++round) {
            int r  = round * 32 + rr;
            int gt = tw + r;
            bf16x8 v = {0, 0, 0, 0, 0, 0, 0, 0};
            if (gt >= 0)
                v = *(const bf16x8*)(prev + ((size_t)b * T_LEN + gt) * NCH + co);
            *(bf16x8*)(&A[sw(r, co)]) = v;
        }
    }

    float skacc0 = 0.f, skacc1 = 0.f;

#pragma unroll 1
    for (int l = 0; l < 6; ++l) {
        const int d = 1 << l;
        const __hip_bfloat16* whid = whid_all + (size_t)(lbase + l) * 16384;
        const __hip_bfloat16* wres = wres_all + (size_t)(lbase + l) * 4096;
        const float* hb = hb_all + (lbase + l) * 128;
        const float* rb = rb_all + (lbase + l) * 64;
        const float* mw = mix_w + (lbase + l) * 64;

        // ---- per-layer weights to registers ----
        bf16x8 aT[4], aS[4], aR[2];
        {
            const __hip_bfloat16* whT = whid + (size_t)(m0 + l15) * 128 + quad * 8;
            const __hip_bfloat16* whS = whT + 64 * 128;
#pragma unroll
            for (int k = 0; k < 4; ++k) {
                aT[k] = *(const bf16x8*)(whT + k * 32);
                aS[k] = *(const bf16x8*)(whS + k * 32);
            }
            const __hip_bfloat16* wrA = wres + (size_t)(m0 + l15) * 64 + quad * 8;
            aR[0] = *(const bf16x8*)(wrA);
            aR[1] = *(const bf16x8*)(wrA + 32);
        }
        f32x4 biasT, biasS, biasR;
#pragma unroll
        for (int r = 0; r < 4; ++r) {
            biasT[r] = hb[m0 + quad * 4 + r];
            biasS[r] = hb[64 + m0 + quad * 4 + r];
            biasR[r] = rb[m0 + quad * 4 + r];
        }
        float mwq[16];
#pragma unroll
        for (int k = 0; k < 4; ++k) {
            float4 m4 = *(const float4*)(mw + quad * 16 + k * 4);
            mwq[k * 4 + 0] = m4.x; mwq[k * 4 + 1] = m4.y;
            mwq[k * 4 + 2] = m4.z; mwq[k * 4 + 3] = m4.w;
        }

        __syncthreads();   // staging / previous epilogue A-writes visible

        // ---- phase 1: GEMM1 + gate ----
#pragma unroll
        for (int ct = 0; ct < 3; ++ct) {
            f32x4 accT[4], accS[4];
#pragma unroll
            for (int nt = 0; nt < 4; ++nt) { accT[nt] = biasT; accS[nt] = biasS; }
#pragma unroll
            for (int ks = 0; ks < 4; ++ks) {
                const int koff = (ks & 1) * 32 + quad * 8;
#pragma unroll
                for (int nt = 0; nt < 4; ++nt) {
                    int trow = ct * 64 + nt * 16 + l15;
                    int prow = trow - d;  prow = prow < 0 ? 0 : prow;
                    int row  = (ks < 2) ? prow : trow;
                    bf16x8 bx = *(const bf16x8*)(&A[sw(row, koff)]);
                    accT[nt] = __builtin_amdgcn_mfma_f32_16x16x32_bf16(aT[ks], bx, accT[nt], 0, 0, 0);
                    accS[nt] = __builtin_amdgcn_mfma_f32_16x16x32_bf16(aS[ks], bx, accS[nt], 0, 0, 0);
                }
            }
#pragma unroll
            for (int nt = 0; nt < 4; ++nt) {
                int trow = ct * 64 + nt * 16 + l15;
                bf16x4 gv;
#pragma unroll
                for (int r = 0; r < 4; ++r) {
                    gv[r] = f2bf(gate_fn(accT[nt][r], accS[nt][r]));
                }
                *(bf16x4*)(&G[sw(trow, m0 + quad * 4)]) = gv;
            }
        }
        __syncthreads();  // G complete, all phase-1 A-reads done

        // ---- phase 2: GEMM2 + in-place residual epilogue ----
#pragma unroll
        for (int ct = 0; ct < 3; ++ct) {
            f32x4 accR[4];
#pragma unroll
            for (int nt = 0; nt < 4; ++nt) accR[nt] = biasR;
#pragma unroll
            for (int ks = 0; ks < 2; ++ks) {
                const int koff = ks * 32 + quad * 8;
#pragma unroll
                for (int nt = 0; nt < 4; ++nt) {
                    int trow = ct * 64 + nt * 16 + l15;
                    bf16x8 bx = *(const bf16x8*)(&G[sw(trow, koff)]);
                    accR[nt] = __builtin_amdgcn_mfma_f32_16x16x32_bf16(aR[ks], bx, accR[nt], 0, 0, 0);
                }
            }
#pragma unroll
            for (int nt = 0; nt < 4; ++nt) {
                int trow = ct * 64 + nt * 16 + l15;
                int idx  = sw(trow, m0 + quad * 4);
                bf16x4 old = *(const bf16x4*)(&A[idx]);
                bool ok = (tw + trow) >= 0;   // causal zero for global t<0
                bf16x4 ov;
#pragma unroll
                for (int r = 0; r < 4; ++r) {
                    float v = accR[nt][r] + bf2f(old[r]);
                    ov[r] = f2bf(ok ? v : 0.f);
                }
                *(bf16x4*)(&A[idx]) = ov;
            }
        }

        // ---- skip->mix partials over output region [64,192) (R5-proven) ----
#pragma unroll
        for (int s = 0; s < 2; ++s) {
            int p = 64 + w4 * 32 + s * 16 + l15;
            bf16x8 g0 = *(const bf16x8*)(&G[sw(p, quad * 16)]);
            bf16x8 g1 = *(const bf16x8*)(&G[sw(p, quad * 16 + 8)]);
            float sv = 0.f;
#pragma unroll
            for (int j = 0; j < 8; ++j) {
                sv += mwq[j]     * bf2f(g0[j]);
                sv += mwq[8 + j] * bf2f(g1[j]);
            }
            if (s == 0) skacc0 += sv; else skacc1 += sv;
        }
    }
    __syncthreads();  // last epilogue visible

    // ---- write output window [t0, t0+128) ----
#pragma unroll
    for (int round = 0; round < 4; ++round) {
        int pr = round * 32 + rr;
        *(bf16x8*)(next + ((size_t)b * T_LEN + t0 + pr) * NCH + co) =
            *(const bf16x8*)(&A[sw(pr + 64, co)]);
    }

    // ---- skip accumulate (quad-reduce, exclusive t-ownership -> plain RMW) ----
    skacc0 += __shfl_xor(skacc0, 16, 64);
    skacc0 += __shfl_xor(skacc0, 32, 64);
    skacc1 += __shfl_xor(skacc1, 16, 64);
    skacc1 += __shfl_xor(skacc1, 32, 64);
    if (quad == 0) {
        acc[(size_t)b * T_LEN + t0 + w4 * 32 + l15]      += skacc0;
        acc[(size_t)b * T_LEN + t0 + w4 * 32 + 16 + l15] += skacc1;
    }
}

// ---------------------------------------------------------------------------
// Single-layer pass for d in {64,128,256}. R4 structure + cheap gate, now at
// 4 blocks/CU (VGPR<=128, LDS 27.6 KB permit it; grid 1024 = exactly 4/CU).
// ---------------------------------------------------------------------------
__global__ __launch_bounds__(256, 4) void layer_mfma_kernel(
    const __hip_bfloat16* __restrict__ prev,   // [B][T][C] bf16
    __hip_bfloat16* __restrict__ next,         // [B][T][C] bf16
    float* __restrict__ acc,                   // [B][T]
    const __hip_bfloat16* __restrict__ whid,   // [128][128] this layer
    const float* __restrict__ hb,              // [128]
    const __hip_bfloat16* __restrict__ wres,   // [64][64]
    const float* __restrict__ rb,              // [64]
    const float* __restrict__ mw,              // [64]
    int d) {
    __shared__ __align__(16) __hip_bfloat16 Xp[64 * 72];
    __shared__ __align__(16) __hip_bfloat16 Xc[64 * 72];
    __shared__ __align__(16) __hip_bfloat16 Gt[64 * 72];

    const int t0   = blockIdx.x << 6;
    const int tid  = threadIdx.x;
    const int lane = tid & 63;
    const int w4   = tid >> 6;
    const int l15  = lane & 15;
    const int quad = lane >> 4;
    const int m0   = w4 * 16;
    const int rr = tid >> 3;
    const int co = (tid & 7) * 8;

    bf16x8 aT[4], aS[4], aR[2];
    {
        const __hip_bfloat16* whT = whid + (size_t)(m0 + l15) * 128 + quad * 8;
        const __hip_bfloat16* whS = whT + 64 * 128;
#pragma unroll
        for (int k = 0; k < 4; ++k) {
            aT[k] = *(const bf16x8*)(whT + k * 32);
            aS[k] = *(const bf16x8*)(whS + k * 32);
        }
        const __hip_bfloat16* wrA = wres + (size_t)(m0 + l15) * 64 + quad * 8;
        aR[0] = *(const bf16x8*)(wrA);
        aR[1] = *(const bf16x8*)(wrA + 32);
    }
    f32x4 biasT, biasS, biasR;
#pragma unroll
    for (int r = 0; r < 4; ++r) {
        biasT[r] = hb[m0 + quad * 4 + r];
        biasS[r] = hb[64 + m0 + quad * 4 + r];
        biasR[r] = rb[m0 + quad * 4 + r];
    }
    float mwq[16];
#pragma unroll
    for (int j = 0; j < 16; ++j) mwq[j] = mw[quad * 16 + j];

    bf16x8 pc[2], pp[2];
#define LOAD_TILE(b)                                                          \
    do {                                                                      \
        const __hip_bfloat16* pb = prev + ((size_t)(b) * T_LEN + t0) * NCH;   \
        _Pragma("unroll")                                                     \
        for (int pass = 0; pass < 2; ++pass) {                                \
            int r = pass * 32 + rr;                                           \
            pc[pass] = *(const bf16x8*)(pb + r * NCH + co);                   \
            int tp = t0 + r - d;                                              \
            bf16x8 z = {0, 0, 0, 0, 0, 0, 0, 0};                              \
            pp[pass] = z;                                                     \
            if (tp >= 0)                                                      \
                pp[pass] = *(const bf16x8*)(prev +                            \
                    ((size_t)(b) * T_LEN + tp) * NCH + co);                   \
        }                                                                     \
    } while (0)

    LOAD_TILE(0);

#pragma unroll
    for (int b = 0; b < 4; ++b) {
#pragma unroll
        for (int pass = 0; pass < 2; ++pass) {
            int r = pass * 32 + rr;
            *(bf16x8*)(&Xc[r * 72 + co]) = pc[pass];
            *(bf16x8*)(&Xp[r * 72 + co]) = pp[pass];
        }
        __syncthreads();                       // barrier A

        if (b < 3) LOAD_TILE(b + 1);

        f32x4 accT[4], accS[4];
#pragma unroll
        for (int nt = 0; nt < 4; ++nt) { accT[nt] = biasT; accS[nt] = biasS; }
#pragma unroll
        for (int ks = 0; ks < 4; ++ks) {
            const __hip_bfloat16* srcb = (ks < 2) ? Xp : Xc;
            const int kk = (ks & 1) * 32 + quad * 8;
#pragma unroll
            for (int nt = 0; nt < 4; ++nt) {
                bf16x8 bx = *(const bf16x8*)(&srcb[(nt * 16 + l15) * 72 + kk]);
                accT[nt] = __builtin_amdgcn_mfma_f32_16x16x32_bf16(aT[ks], bx, accT[nt], 0, 0, 0);
                accS[nt] = __builtin_amdgcn_mfma_f32_16x16x32_bf16(aS[ks], bx, accS[nt], 0, 0, 0);
            }
        }

#pragma unroll
        for (int nt = 0; nt < 4; ++nt) {
            int t = nt * 16 + l15;
#pragma unroll
            for (int r = 0; r < 4; ++r) {
                Gt[t * 72 + m0 + quad * 4 + r] =
                    __float2bfloat16(gate_fn(accT[nt][r], accS[nt][r]));
            }
        }

        bf16x4 curres[4];
#pragma unroll
        for (int nt = 0; nt < 4; ++nt) {
            curres[nt] = *(const bf16x4*)(&Xc[(nt * 16 + l15) * 72 + m0 + quad * 4]);
        }
        __syncthreads();                       // barrier B

        f32x4 accR[4];
#pragma unroll
        for (int nt = 0; nt < 4; ++nt) accR[nt] = biasR;
#pragma unroll
        for (int ks = 0; ks < 2; ++ks) {
            const int kk = ks * 32 + quad * 8;
#pragma unroll
            for (int nt = 0; nt < 4; ++nt) {
                bf16x8 bx = *(const bf16x8*)(&Gt[(nt * 16 + l15) * 72 + kk]);
                accR[nt] = __builtin_amdgcn_mfma_f32_16x16x32_bf16(aR[ks], bx, accR[nt], 0, 0, 0);
            }
        }

        __hip_bfloat16* nb = next + ((size_t)b * T_LEN + t0) * NCH;
#pragma unroll
        for (int nt = 0; nt < 4; ++nt) {
            int t = nt * 16 + l15;
            bf16x4 ov;
#pragma unroll
            for (int r = 0; r < 4; ++r) {
                ov[r] = f2bf(accR[nt][r] + bf2f(curres[nt][r]));
            }
            *(bf16x4*)(nb + t * NCH + m0 + quad * 4) = ov;
        }

        {
            int t = w4 * 16 + l15;
            bf16x8 g0 = *(const bf16x8*)(&Gt[t * 72 + quad * 16]);
            bf16x8 g1 = *(const bf16x8*)(&Gt[t * 72 + quad * 16 + 8]);
            float s = 0.f;
#pragma unroll
            for (int j = 0; j < 8; ++j) {
                s += mwq[j]     * bf2f(g0[j]);
                s += mwq[8 + j] * bf2f(g1[j]);
            }
            s += __shfl_xor(s, 16, 64);
            s += __shfl_xor(s, 32, 64);
            if (quad == 0)
                acc[(size_t)b * T_LEN + t0 + t] += s;
        }
    }
#undef LOAD_TILE
}

// ---------------------------------------------------------------------------
// Last layer (17, d=256): GEMM1 + gate + skip only, fused finalize -> out.
// ---------------------------------------------------------------------------
__global__ __launch_bounds__(256, 4) void last_layer_kernel(
    const __hip_bfloat16* __restrict__ prev,   // [B][T][C]
    const float* __restrict__ acc,             // [B][T]
    float* __restrict__ out,                   // [B][T] fp32
    const __hip_bfloat16* __restrict__ whid,   // [128][128] layer 17
    const float* __restrict__ hb,              // [128]
    const float* __restrict__ mw,              // [64]
    const float* __restrict__ mix_b,           // [1]
    int d) {
    __shared__ __align__(16) __hip_bfloat16 Xp[64 * 72];
    __shared__ __align__(16) __hip_bfloat16 Xc[64 * 72];
    __shared__ float skb[4 * 64];

    const int t0   = blockIdx.x << 6;
    const int tid  = threadIdx.x;
    const int lane = tid & 63;
    const int w4   = tid >> 6;
    const int l15  = lane & 15;
    const int quad = lane >> 4;
    const int m0   = w4 * 16;
    const int rr = tid >> 3;
    const int co = (tid & 7) * 8;

    bf16x8 aT[4], aS[4];
    {
        const __hip_bfloat16* whT = whid + (size_t)(m0 + l15) * 128 + quad * 8;
        const __hip_bfloat16* whS = whT + 64 * 128;
#pragma unroll
        for (int k = 0; k < 4; ++k) {
            aT[k] = *(const bf16x8*)(whT + k * 32);
            aS[k] = *(const bf16x8*)(whS + k * 32);
        }
    }
    f32x4 biasT, biasS;
    float mwv[4];
#pragma unroll
    for (int r = 0; r < 4; ++r) {
        biasT[r] = hb[m0 + quad * 4 + r];
        biasS[r] = hb[64 + m0 + quad * 4 + r];
        mwv[r]   = mw[m0 + quad * 4 + r];
    }
    const float mb = mix_b[0];

    bf16x8 pc[2], pp[2];
#define LOAD_TILE(b)                                                          \
    do {                                                                      \
        const __hip_bfloat16* pb = prev + ((size_t)(b) * T_LEN + t0) * NCH;   \
        _Pragma("unroll")                                                     \
        for (int pass = 0; pass < 2; ++pass) {                                \
            int r = pass * 32 + rr;                                           \
            pc[pass] = *(const bf16x8*)(pb + r * NCH + co);                   \
            int tp = t0 + r - d;                                              \
            bf16x8 z = {0, 0, 0, 0, 0, 0, 0, 0};                              \
            pp[pass] = z;                                                     \
            if (tp >= 0)                                                      \
                pp[pass] = *(const bf16x8*)(prev +                            \
                    ((size_t)(b) * T_LEN + tp) * NCH + co);                   \
        }                                                                     \
    } while (0)

    LOAD_TILE(0);

#pragma unroll
    for (int b = 0; b < 4; ++b) {
#pragma unroll
        for (int pass = 0; pass < 2; ++pass) {
            int r = pass * 32 + rr;
            *(bf16x8*)(&Xc[r * 72 + co]) = pc[pass];
            *(bf16x8*)(&Xp[r * 72 + co]) = pp[pass];
        }
        __syncthreads();                       // barrier A

        if (b < 3) LOAD_TILE(b + 1);

        f32x4 accT[4], accS[4];
#pragma unroll
        for (int nt = 0; nt < 4; ++nt) { accT[nt] = biasT; accS[nt] = biasS; }
#pragma unroll
        for (int ks = 0; ks < 4; ++ks) {
            const __hip_bfloat16* srcb = (ks < 2) ? Xp : Xc;
            const int kk = (ks & 1) * 32 + quad * 8;
#pragma unroll
            for (int nt = 0; nt < 4; ++nt) {
                bf16x8 bx = *(const bf16x8*)(&srcb[(nt * 16 + l15) * 72 + kk]);
                accT[nt] = __builtin_amdgcn_mfma_f32_16x16x32_bf16(aT[ks], bx, accT[nt], 0, 0, 0);
                accS[nt] = __builtin_amdgcn_mfma_f32_16x16x32_bf16(aS[ks], bx, accS[nt], 0, 0, 0);
            }
        }

#pragma unroll
        for (int nt = 0; nt < 4; ++nt) {
            float sv = 0.f;
#pragma unroll
            for (int r = 0; r < 4; ++r) {
                sv += mwv[r] * gate_fn(accT[nt][r], accS[nt][r]);
            }
            sv += __shfl_xor(sv, 16, 64);
            sv += __shfl_xor(sv, 32, 64);
            if (quad == 0)
                skb[w4 * 64 + nt * 16 + l15] = sv;
        }
        __syncthreads();                       // barrier B

        if (tid < 64) {
            float tot = skb[tid] + skb[64 + tid] + skb[128 + tid] + skb[192 + tid];
            out[(size_t)b * T_LEN + t0 + tid] =
                acc[(size_t)b * T_LEN + t0 + tid] + tot + mb;
        }
    }
#undef LOAD_TILE
}

// ---------------------------------------------------------------------------
extern "C" void kernel_launch(void* const* d_in, const int* in_sizes, int n_in,
                              void* d_out, int out_size, void* d_ws, size_t ws_size,
                              hipStream_t stream) {
    const float* x     = (const float*)d_in[0];
    const float* in_w  = (const float*)d_in[1];
    const float* in_b  = (const float*)d_in[2];
    const float* hid_w = (const float*)d_in[3];  // [18][128][64][2]
    const float* hid_b = (const float*)d_in[4];  // [18][128]
    const float* res_w = (const float*)d_in[5];  // [18][64][64][1]
    const float* res_b = (const float*)d_in[6];  // [18][64]
    const float* mix_w = (const float*)d_in[7];  // [1152]
    const float* mix_b = (const float*)d_in[8];  // [1]
    float* out = (float*)d_out;

    // ws: actA 32M | actB 32M | acc 1M | whid | wres
    const size_t act_elems = 4ull * T_LEN * NCH;     // 16M bf16 = 32 MB
    __hip_bfloat16* actA = (__hip_bfloat16*)d_ws;
    __hip_bfloat16* actB = actA + act_elems;
    float* acc = (float*)(actB + act_elems);         // [B][T] = 1 MB
    __hip_bfloat16* whid = (__hip_bfloat16*)(acc + 4ull * T_LEN);
    __hip_bfloat16* wres = whid + (size_t)NLAYER * 128 * 128;

    hipMemsetAsync(acc, 0, 4ull * T_LEN * sizeof(float), stream);

    convert_weights_kernel<<<1152, 256, 0, stream>>>(hid_w, res_w, whid, wres);

    // P0: input conv + layers 0-5 (d=1..32) fused -> actA
    fused6_kernel<<<2048, 256, 0, stream>>>(
        x, actA, acc, whid, hid_b, wres, res_b, mix_w, in_w, in_b, 0, 1);

    // P1-P3: layers 6,7,8 (d=64,128,256)
    layer_mfma_kernel<<<1024, 256, 0, stream>>>(
        actA, actB, acc, whid + 6 * 16384, hid_b + 6 * 128,
        wres + 6 * 4096, res_b + 6 * 64, mix_w + 6 * 64, 64);
    layer_mfma_kernel<<<1024, 256, 0, stream>>>(
        actB, actA, acc, whid + 7 * 16384, hid_b + 7 * 128,
        wres + 7 * 4096, res_b + 7 * 64, mix_w + 7 * 64, 128);
    layer_mfma_kernel<<<1024, 256, 0, stream>>>(
        actA, actB, acc, whid + 8 * 16384, hid_b + 8 * 128,
        wres + 8 * 4096, res_b + 8 * 64, mix_w + 8 * 64, 256);

    // P4: layers 9-14 (d=1..32) fused -> actA
    fused6_kernel<<<2048, 256, 0, stream>>>(
        actB, actA, acc, whid, hid_b, wres, res_b, mix_w, in_w, in_b, 9, 0);

    // P5-P6: layers 15,16 (d=64,128)
    layer_mfma_kernel<<<1024, 256, 0, stream>>>(
        actA, actB, acc, whid + 15 * 16384, hid_b + 15 * 128,
        wres + 15 * 4096, res_b + 15 * 64, mix_w + 15 * 64, 64);
    layer_mfma_kernel<<<1024, 256, 0, stream>>>(
        actB, actA, acc, whid + 16 * 16384, hid_b + 16 * 128,
        wres + 16 * 4096, res_b + 16 * 64, mix_w + 16 * 64, 128);

    // P7: layer 17 (d=256) + finalize -> out
    last_layer_kernel<<<1024, 256, 0, stream>>>(
        actA, acc, out, whid + 17 * 16384, hid_b + 17 * 128,
        mix_w + 17 * 64, mix_b, 256);
}

// Round 10
// 567.355 us; speedup vs baseline: 1.1751x; 1.1751x over previous
//
#include <hip/hip_runtime.h>
#include <hip/hip_bf16.h>
#include <math.h>

#define NCH 64       // C
#define T_LEN 65536
#define NLAYER 18

typedef __attribute__((ext_vector_type(8))) short bf16x8;   // 8 bf16 = 4 VGPRs
typedef __attribute__((ext_vector_type(4))) short bf16x4;   // 4 bf16 = 2 VGPRs
typedef __attribute__((ext_vector_type(4))) float f32x4;

static __device__ __forceinline__ float bf2f(short s) {
    union { short u[2]; float f; } v;
    v.u[0] = 0; v.u[1] = s;
    return v.f;
}
static __device__ __forceinline__ short f2bf(float f) {
    __hip_bfloat16 h = __float2bfloat16(f);
    return *(short*)&h;
}
// gated = tanh(x)*sigmoid(y) = (e^{2x}-1) / ((e^{2x}+1)(1+e^{-y}))
// 2 exp + 1 rcp. Correctness validated in passing R7.
static __device__ __forceinline__ float gate_fn(float x, float y) {
    x = fminf(fmaxf(x, -15.f), 15.f);
    float e2 = __expf(2.f * x);
    float em = __expf(-y);
    return (e2 - 1.f) * __builtin_amdgcn_rcpf((e2 + 1.f) * (1.f + em));
}
// XOR-swizzled LDS index for pitch-64 bf16 rows (128 B = 8 chunks of 16 B).
// Bijective per row; every access site goes through sw(). Validated R7.
static __device__ __forceinline__ int sw(int row, int elem) {
    return (row << 6) + ((((elem >> 3) ^ (row & 7)) << 3) | (elem & 7));
}

// ---------------------------------------------------------------------------
// whid[l][o][k]: k<64 -> hid_w[l][o][k][0] (past tap), k>=64 -> [k-64][1] (cur)
// ---------------------------------------------------------------------------
__global__ void convert_weights_kernel(const float* __restrict__ hid_w,
                                       const float* __restrict__ res_w,
                                       __hip_bfloat16* __restrict__ whid,
                                       __hip_bfloat16* __restrict__ wres) {
    int gid = blockIdx.x * 256 + threadIdx.x;
    if (gid < NLAYER * 128 * 128) {
        int l   = gid >> 14;
        int rem = gid & 16383;
        int o   = rem >> 7;
        int k   = rem & 127;
        float v = (k < 64)
            ? hid_w[((l * 128 + o) * 64 + k) * 2]
            : hid_w[((l * 128 + o) * 64 + (k - 64)) * 2 + 1];
        whid[gid] = __float2bfloat16(v);
    }
    if (gid < NLAYER * 64 * 64) {
        wres[gid] = __float2bfloat16(res_w[gid]);
    }
}

// ---------------------------------------------------------------------------
// Fused 6-layer pass — VERBATIM from passing R7 (dur 190 us, absmax 0.028).
// Window [t0-64, t0+128) = 192 rows; 48 KB swizzled LDS; 3 blocks/CU.
// A = residual stream in-place, G = gated. Skip->mix: per-layer scalar
// reduction from G (bf16), accumulated in 2 regs, end-of-kernel quad shuffle.
// NOTE: register-skip fold (R8/R9) fails with absmax ~0.21 — do not retry.
// ---------------------------------------------------------------------------
__global__ __launch_bounds__(256, 3) void fused6_kernel(
    const void* __restrict__ src,                 // fp32 x | bf16 prev
    __hip_bfloat16* __restrict__ next,            // [B][T][C]
    float* __restrict__ acc,                      // [B][T]
    const __hip_bfloat16* __restrict__ whid_all,  // [18][128][128]
    const float* __restrict__ hb_all,             // [18][128]
    const __hip_bfloat16* __restrict__ wres_all,  // [18][64][64]
    const float* __restrict__ rb_all,             // [18][64]
    const float* __restrict__ mix_w,              // [1152]
    const float* __restrict__ in_w,               // [64]
    const float* __restrict__ in_b,               // [64]
    int lbase, int is_first) {
    __shared__ __align__(16) __hip_bfloat16 A[192 * 64];
    __shared__ __align__(16) __hip_bfloat16 G[192 * 64];

    const int b    = blockIdx.x >> 9;          // 512 windows per batch
    const int widx = blockIdx.x & 511;
    const int t0   = widx << 7;
    const int tw   = t0 - 64;

    const int tid  = threadIdx.x;
    const int lane = tid & 63;
    const int w4   = tid >> 6;
    const int l15  = lane & 15;
    const int quad = lane >> 4;
    const int m0   = w4 * 16;
    const int rr   = tid >> 3;                 // 0..31
    const int co   = (tid & 7) * 8;

    // ---- stage input window [tw, tw+192) ----
    if (is_first) {
        const float* x = (const float*)src;
        float iw[8], ib[8];
#pragma unroll
        for (int j = 0; j < 8; ++j) { iw[j] = in_w[co + j]; ib[j] = in_b[co + j]; }
#pragma unroll
        for (int round = 0; round < 6; ++round) {
            int r  = round * 32 + rr;
            int gt = tw + r;
            bf16x8 v = {0, 0, 0, 0, 0, 0, 0, 0};
            if (gt >= 0) {
                float xv = x[(size_t)b * T_LEN + gt];
#pragma unroll
                for (int j = 0; j < 8; ++j) v[j] = f2bf(iw[j] * xv + ib[j]);
            }
            *(bf16x8*)(&A[sw(r, co)]) = v;
        }
    } else {
        const __hip_bfloat16* prev = (const __hip_bfloat16*)src;
#pragma unroll
        for (int round = 0; round < 6; ++round) {
            int r  = round * 32 + rr;
            int gt = tw + r;
            bf16x8 v = {0, 0, 0, 0, 0, 0, 0, 0};
            if (gt >= 0)
                v = *(const bf16x8*)(prev + ((size_t)b * T_LEN + gt) * NCH + co);
            *(bf16x8*)(&A[sw(r, co)]) = v;
        }
    }

    float skacc0 = 0.f, skacc1 = 0.f;

#pragma unroll 1
    for (int l = 0; l < 6; ++l) {
        const int d = 1 << l;
        const __hip_bfloat16* whid = whid_all + (size_t)(lbase + l) * 16384;
        const __hip_bfloat16* wres = wres_all + (size_t)(lbase + l) * 4096;
        const float* hb = hb_all + (lbase + l) * 128;
        const float* rb = rb_all + (lbase + l) * 64;
        const float* mw = mix_w + (lbase + l) * 64;

        // ---- per-layer weights to registers ----
        bf16x8 aT[4], aS[4], aR[2];
        {
            const __hip_bfloat16* whT = whid + (size_t)(m0 + l15) * 128 + quad * 8;
            const __hip_bfloat16* whS = whT + 64 * 128;
#pragma unroll
            for (int k = 0; k < 4; ++k) {
                aT[k] = *(const bf16x8*)(whT + k * 32);
                aS[k] = *(const bf16x8*)(whS + k * 32);
            }
            const __hip_bfloat16* wrA = wres + (size_t)(m0 + l15) * 64 + quad * 8;
            aR[0] = *(const bf16x8*)(wrA);
            aR[1] = *(const bf16x8*)(wrA + 32);
        }
        f32x4 biasT, biasS, biasR;
#pragma unroll
        for (int r = 0; r < 4; ++r) {
            biasT[r] = hb[m0 + quad * 4 + r];
            biasS[r] = hb[64 + m0 + quad * 4 + r];
            biasR[r] = rb[m0 + quad * 4 + r];
        }
        float mwq[16];
#pragma unroll
        for (int k = 0; k < 4; ++k) {
            float4 m4 = *(const float4*)(mw + quad * 16 + k * 4);
            mwq[k * 4 + 0] = m4.x; mwq[k * 4 + 1] = m4.y;
            mwq[k * 4 + 2] = m4.z; mwq[k * 4 + 3] = m4.w;
        }

        __syncthreads();   // staging / previous epilogue A-writes visible

        // ---- phase 1: GEMM1 + gate ----
#pragma unroll
        for (int ct = 0; ct < 3; ++ct) {
            f32x4 accT[4], accS[4];
#pragma unroll
            for (int nt = 0; nt < 4; ++nt) { accT[nt] = biasT; accS[nt] = biasS; }
#pragma unroll
            for (int ks = 0; ks < 4; ++ks) {
                const int koff = (ks & 1) * 32 + quad * 8;
#pragma unroll
                for (int nt = 0; nt < 4; ++nt) {
                    int trow = ct * 64 + nt * 16 + l15;
                    int prow = trow - d;  prow = prow < 0 ? 0 : prow;
                    int row  = (ks < 2) ? prow : trow;
                    bf16x8 bx = *(const bf16x8*)(&A[sw(row, koff)]);
                    accT[nt] = __builtin_amdgcn_mfma_f32_16x16x32_bf16(aT[ks], bx, accT[nt], 0, 0, 0);
                    accS[nt] = __builtin_amdgcn_mfma_f32_16x16x32_bf16(aS[ks], bx, accS[nt], 0, 0, 0);
                }
            }
#pragma unroll
            for (int nt = 0; nt < 4; ++nt) {
                int trow = ct * 64 + nt * 16 + l15;
                bf16x4 gv;
#pragma unroll
                for (int r = 0; r < 4; ++r) {
                    gv[r] = f2bf(gate_fn(accT[nt][r], accS[nt][r]));
                }
                *(bf16x4*)(&G[sw(trow, m0 + quad * 4)]) = gv;
            }
        }
        __syncthreads();  // G complete, all phase-1 A-reads done

        // ---- phase 2: GEMM2 + in-place residual epilogue ----
#pragma unroll
        for (int ct = 0; ct < 3; ++ct) {
            f32x4 accR[4];
#pragma unroll
            for (int nt = 0; nt < 4; ++nt) accR[nt] = biasR;
#pragma unroll
            for (int ks = 0; ks < 2; ++ks) {
                const int koff = ks * 32 + quad * 8;
#pragma unroll
                for (int nt = 0; nt < 4; ++nt) {
                    int trow = ct * 64 + nt * 16 + l15;
                    bf16x8 bx = *(const bf16x8*)(&G[sw(trow, koff)]);
                    accR[nt] = __builtin_amdgcn_mfma_f32_16x16x32_bf16(aR[ks], bx, accR[nt], 0, 0, 0);
                }
            }
#pragma unroll
            for (int nt = 0; nt < 4; ++nt) {
                int trow = ct * 64 + nt * 16 + l15;
                int idx  = sw(trow, m0 + quad * 4);
                bf16x4 old = *(const bf16x4*)(&A[idx]);
                bool ok = (tw + trow) >= 0;   // causal zero for global t<0
                bf16x4 ov;
#pragma unroll
                for (int r = 0; r < 4; ++r) {
                    float v = accR[nt][r] + bf2f(old[r]);
                    ov[r] = f2bf(ok ? v : 0.f);
                }
                *(bf16x4*)(&A[idx]) = ov;
            }
        }

        // ---- skip->mix partials over output region [64,192) (R5/R7-proven) ----
#pragma unroll
        for (int s = 0; s < 2; ++s) {
            int p = 64 + w4 * 32 + s * 16 + l15;
            bf16x8 g0 = *(const bf16x8*)(&G[sw(p, quad * 16)]);
            bf16x8 g1 = *(const bf16x8*)(&G[sw(p, quad * 16 + 8)]);
            float sv = 0.f;
#pragma unroll
            for (int j = 0; j < 8; ++j) {
                sv += mwq[j]     * bf2f(g0[j]);
                sv += mwq[8 + j] * bf2f(g1[j]);
            }
            if (s == 0) skacc0 += sv; else skacc1 += sv;
        }
    }
    __syncthreads();  // last epilogue visible

    // ---- write output window [t0, t0+128) ----
#pragma unroll
    for (int round = 0; round < 4; ++round) {
        int pr = round * 32 + rr;
        *(bf16x8*)(next + ((size_t)b * T_LEN + t0 + pr) * NCH + co) =
            *(const bf16x8*)(&A[sw(pr + 64, co)]);
    }

    // ---- skip accumulate (quad-reduce, exclusive t-ownership -> plain RMW) ----
    skacc0 += __shfl_xor(skacc0, 16, 64);
    skacc0 += __shfl_xor(skacc0, 32, 64);
    skacc1 += __shfl_xor(skacc1, 16, 64);
    skacc1 += __shfl_xor(skacc1, 32, 64);
    if (quad == 0) {
        acc[(size_t)b * T_LEN + t0 + w4 * 32 + l15]      += skacc0;
        acc[(size_t)b * T_LEN + t0 + w4 * 32 + 16 + l15] += skacc1;
    }
}

// ---------------------------------------------------------------------------
// Single-layer pass for d in {64,128,256}. R5-proven config (bounds 2,
// 4-batch pipeline, weights hoisted) + gate_fn (correctness proven R7).
// ---------------------------------------------------------------------------
__global__ __launch_bounds__(256, 2) void layer_mfma_kernel(
    const __hip_bfloat16* __restrict__ prev,   // [B][T][C] bf16
    __hip_bfloat16* __restrict__ next,         // [B][T][C] bf16
    float* __restrict__ acc,                   // [B][T]
    const __hip_bfloat16* __restrict__ whid,   // [128][128] this layer
    const float* __restrict__ hb,              // [128]
    const __hip_bfloat16* __restrict__ wres,   // [64][64]
    const float* __restrict__ rb,              // [64]
    const float* __restrict__ mw,              // [64]
    int d) {
    __shared__ __align__(16) __hip_bfloat16 Xp[64 * 72];
    __shared__ __align__(16) __hip_bfloat16 Xc[64 * 72];
    __shared__ __align__(16) __hip_bfloat16 Gt[64 * 72];

    const int t0   = blockIdx.x << 6;
    const int tid  = threadIdx.x;
    const int lane = tid & 63;
    const int w4   = tid >> 6;
    const int l15  = lane & 15;
    const int quad = lane >> 4;
    const int m0   = w4 * 16;
    const int rr = tid >> 3;
    const int co = (tid & 7) * 8;

    bf16x8 aT[4], aS[4], aR[2];
    {
        const __hip_bfloat16* whT = whid + (size_t)(m0 + l15) * 128 + quad * 8;
        const __hip_bfloat16* whS = whT + 64 * 128;
#pragma unroll
        for (int k = 0; k < 4; ++k) {
            aT[k] = *(const bf16x8*)(whT + k * 32);
            aS[k] = *(const bf16x8*)(whS + k * 32);
        }
        const __hip_bfloat16* wrA = wres + (size_t)(m0 + l15) * 64 + quad * 8;
        aR[0] = *(const bf16x8*)(wrA);
        aR[1] = *(const bf16x8*)(wrA + 32);
    }
    f32x4 biasT, biasS, biasR;
#pragma unroll
    for (int r = 0; r < 4; ++r) {
        biasT[r] = hb[m0 + quad * 4 + r];
        biasS[r] = hb[64 + m0 + quad * 4 + r];
        biasR[r] = rb[m0 + quad * 4 + r];
    }
    float mwq[16];
#pragma unroll
    for (int j = 0; j < 16; ++j) mwq[j] = mw[quad * 16 + j];

    bf16x8 pc[2], pp[2];
#define LOAD_TILE(b)                                                          \
    do {                                                                      \
        const __hip_bfloat16* pb = prev + ((size_t)(b) * T_LEN + t0) * NCH;   \
        _Pragma("unroll")                                                     \
        for (int pass = 0; pass < 2; ++pass) {                                \
            int r = pass * 32 + rr;                                           \
            pc[pass] = *(const bf16x8*)(pb + r * NCH + co);                   \
            int tp = t0 + r - d;                                              \
            bf16x8 z = {0, 0, 0, 0, 0, 0, 0, 0};                              \
            pp[pass] = z;                                                     \
            if (tp >= 0)                                                      \
                pp[pass] = *(const bf16x8*)(prev +                            \
                    ((size_t)(b) * T_LEN + tp) * NCH + co);                   \
        }                                                                     \
    } while (0)

    LOAD_TILE(0);

#pragma unroll
    for (int b = 0; b < 4; ++b) {
#pragma unroll
        for (int pass = 0; pass < 2; ++pass) {
            int r = pass * 32 + rr;
            *(bf16x8*)(&Xc[r * 72 + co]) = pc[pass];
            *(bf16x8*)(&Xp[r * 72 + co]) = pp[pass];
        }
        __syncthreads();                       // barrier A

        if (b < 3) LOAD_TILE(b + 1);

        f32x4 accT[4], accS[4];
#pragma unroll
        for (int nt = 0; nt < 4; ++nt) { accT[nt] = biasT; accS[nt] = biasS; }
#pragma unroll
        for (int ks = 0; ks < 4; ++ks) {
            const __hip_bfloat16* srcb = (ks < 2) ? Xp : Xc;
            const int kk = (ks & 1) * 32 + quad * 8;
#pragma unroll
            for (int nt = 0; nt < 4; ++nt) {
                bf16x8 bx = *(const bf16x8*)(&srcb[(nt * 16 + l15) * 72 + kk]);
                accT[nt] = __builtin_amdgcn_mfma_f32_16x16x32_bf16(aT[ks], bx, accT[nt], 0, 0, 0);
                accS[nt] = __builtin_amdgcn_mfma_f32_16x16x32_bf16(aS[ks], bx, accS[nt], 0, 0, 0);
            }
        }

#pragma unroll
        for (int nt = 0; nt < 4; ++nt) {
            int t = nt * 16 + l15;
#pragma unroll
            for (int r = 0; r < 4; ++r) {
                Gt[t * 72 + m0 + quad * 4 + r] =
                    __float2bfloat16(gate_fn(accT[nt][r], accS[nt][r]));
            }
        }

        bf16x4 curres[4];
#pragma unroll
        for (int nt = 0; nt < 4; ++nt) {
            curres[nt] = *(const bf16x4*)(&Xc[(nt * 16 + l15) * 72 + m0 + quad * 4]);
        }
        __syncthreads();                       // barrier B

        f32x4 accR[4];
#pragma unroll
        for (int nt = 0; nt < 4; ++nt) accR[nt] = biasR;
#pragma unroll
        for (int ks = 0; ks < 2; ++ks) {
            const int kk = ks * 32 + quad * 8;
#pragma unroll
            for (int nt = 0; nt < 4; ++nt) {
                bf16x8 bx = *(const bf16x8*)(&Gt[(nt * 16 + l15) * 72 + kk]);
                accR[nt] = __builtin_amdgcn_mfma_f32_16x16x32_bf16(aR[ks], bx, accR[nt], 0, 0, 0);
            }
        }

        __hip_bfloat16* nb = next + ((size_t)b * T_LEN + t0) * NCH;
#pragma unroll
        for (int nt = 0; nt < 4; ++nt) {
            int t = nt * 16 + l15;
            bf16x4 ov;
#pragma unroll
            for (int r = 0; r < 4; ++r) {
                ov[r] = f2bf(accR[nt][r] + bf2f(curres[nt][r]));
            }
            *(bf16x4*)(nb + t * NCH + m0 + quad * 4) = ov;
        }

        {
            int t = w4 * 16 + l15;
            bf16x8 g0 = *(const bf16x8*)(&Gt[t * 72 + quad * 16]);
            bf16x8 g1 = *(const bf16x8*)(&Gt[t * 72 + quad * 16 + 8]);
            float s = 0.f;
#pragma unroll
            for (int j = 0; j < 8; ++j) {
                s += mwq[j]     * bf2f(g0[j]);
                s += mwq[8 + j] * bf2f(g1[j]);
            }
            s += __shfl_xor(s, 16, 64);
            s += __shfl_xor(s, 32, 64);
            if (quad == 0)
                acc[(size_t)b * T_LEN + t0 + t] += s;
        }
    }
#undef LOAD_TILE
}

// ---------------------------------------------------------------------------
// Last layer (17, d=256): GEMM1 + gate + skip only, fused finalize -> out.
// ---------------------------------------------------------------------------
__global__ __launch_bounds__(256, 2) void last_layer_kernel(
    const __hip_bfloat16* __restrict__ prev,   // [B][T][C]
    const float* __restrict__ acc,             // [B][T]
    float* __restrict__ out,                   // [B][T] fp32
    const __hip_bfloat16* __restrict__ whid,   // [128][128] layer 17
    const float* __restrict__ hb,              // [128]
    const float* __restrict__ mw,              // [64]
    const float* __restrict__ mix_b,           // [1]
    int d) {
    __shared__ __align__(16) __hip_bfloat16 Xp[64 * 72];
    __shared__ __align__(16) __hip_bfloat16 Xc[64 * 72];
    __shared__ float skb[4 * 64];

    const int t0   = blockIdx.x << 6;
    const int tid  = threadIdx.x;
    const int lane = tid & 63;
    const int w4   = tid >> 6;
    const int l15  = lane & 15;
    const int quad = lane >> 4;
    const int m0   = w4 * 16;
    const int rr = tid >> 3;
    const int co = (tid & 7) * 8;

    bf16x8 aT[4], aS[4];
    {
        const __hip_bfloat16* whT = whid + (size_t)(m0 + l15) * 128 + quad * 8;
        const __hip_bfloat16* whS = whT + 64 * 128;
#pragma unroll
        for (int k = 0; k < 4; ++k) {
            aT[k] = *(const bf16x8*)(whT + k * 32);
            aS[k] = *(const bf16x8*)(whS + k * 32);
        }
    }
    f32x4 biasT, biasS;
    float mwv[4];
#pragma unroll
    for (int r = 0; r < 4; ++r) {
        biasT[r] = hb[m0 + quad * 4 + r];
        biasS[r] = hb[64 + m0 + quad * 4 + r];
        mwv[r]   = mw[m0 + quad * 4 + r];
    }
    const float mb = mix_b[0];

    bf16x8 pc[2], pp[2];
#define LOAD_TILE(b)                                                          \
    do {                                                                      \
        const __hip_bfloat16* pb = prev + ((size_t)(b) * T_LEN + t0) * NCH;   \
        _Pragma("unroll")                                                     \
        for (int pass = 0; pass < 2; ++pass) {                                \
            int r = pass * 32 + rr;                                           \
            pc[pass] = *(const bf16x8*)(pb + r * NCH + co);                   \
            int tp = t0 + r - d;                                              \
            bf16x8 z = {0, 0, 0, 0, 0, 0, 0, 0};                              \
            pp[pass] = z;                                                     \
            if (tp >= 0)                                                      \
                pp[pass] = *(const bf16x8*)(prev +                            \
                    ((size_t)(b) * T_LEN + tp) * NCH + co);                   \
        }                                                                     \
    } while (0)

    LOAD_TILE(0);

#pragma unroll
    for (int b = 0; b < 4; ++b) {
#pragma unroll
        for (int pass = 0; pass < 2; ++pass) {
            int r = pass * 32 + rr;
            *(bf16x8*)(&Xc[r * 72 + co]) = pc[pass];
            *(bf16x8*)(&Xp[r * 72 + co]) = pp[pass];
        }
        __syncthreads();                       // barrier A

        if (b < 3) LOAD_TILE(b + 1);

        f32x4 accT[4], accS[4];
#pragma unroll
        for (int nt = 0; nt < 4; ++nt) { accT[nt] = biasT; accS[nt] = biasS; }
#pragma unroll
        for (int ks = 0; ks < 4; ++ks) {
            const __hip_bfloat16* srcb = (ks < 2) ? Xp : Xc;
            const int kk = (ks & 1) * 32 + quad * 8;
#pragma unroll
            for (int nt = 0; nt < 4; ++nt) {
                bf16x8 bx = *(const bf16x8*)(&srcb[(nt * 16 + l15) * 72 + kk]);
                accT[nt] = __builtin_amdgcn_mfma_f32_16x16x32_bf16(aT[ks], bx, accT[nt], 0, 0, 0);
                accS[nt] = __builtin_amdgcn_mfma_f32_16x16x32_bf16(aS[ks], bx, accS[nt], 0, 0, 0);
            }
        }

#pragma unroll
        for (int nt = 0; nt < 4; ++nt) {
            float sv = 0.f;
#pragma unroll
            for (int r = 0; r < 4; ++r) {
                sv += mwv[r] * gate_fn(accT[nt][r], accS[nt][r]);
            }
            sv += __shfl_xor(sv, 16, 64);
            sv += __shfl_xor(sv, 32, 64);
            if (quad == 0)
                skb[w4 * 64 + nt * 16 + l15] = sv;
        }
        __syncthreads();                       // barrier B

        if (tid < 64) {
            float tot = skb[tid] + skb[64 + tid] + skb[128 + tid] + skb[192 + tid];
            out[(size_t)b * T_LEN + t0 + tid] =
                acc[(size_t)b * T_LEN + t0 + tid] + tot + mb;
        }
    }
#undef LOAD_TILE
}

// ---------------------------------------------------------------------------
extern "C" void kernel_launch(void* const* d_in, const int* in_sizes, int n_in,
                              void* d_out, int out_size, void* d_ws, size_t ws_size,
                              hipStream_t stream) {
    const float* x     = (const float*)d_in[0];
    const float* in_w  = (const float*)d_in[1];
    const float* in_b  = (const float*)d_in[2];
    const float* hid_w = (const float*)d_in[3];  // [18][128][64][2]
    const float* hid_b = (const float*)d_in[4];  // [18][128]
    const float* res_w = (const float*)d_in[5];  // [18][64][64][1]
    const float* res_b = (const float*)d_in[6];  // [18][64]
    const float* mix_w = (const float*)d_in[7];  // [1152]
    const float* mix_b = (const float*)d_in[8];  // [1]
    float* out = (float*)d_out;

    // ws: actA 32M | actB 32M | acc 1M | whid | wres
    const size_t act_elems = 4ull * T_LEN * NCH;     // 16M bf16 = 32 MB
    __hip_bfloat16* actA = (__hip_bfloat16*)d_ws;
    __hip_bfloat16* actB = actA + act_elems;
    float* acc = (float*)(actB + act_elems);         // [B][T] = 1 MB
    __hip_bfloat16* whid = (__hip_bfloat16*)(acc + 4ull * T_LEN);
    __hip_bfloat16* wres = whid + (size_t)NLAYER * 128 * 128;

    hipMemsetAsync(acc, 0, 4ull * T_LEN * sizeof(float), stream);

    convert_weights_kernel<<<1152, 256, 0, stream>>>(hid_w, res_w, whid, wres);

    // P0: input conv + layers 0-5 (d=1..32) fused -> actA
    fused6_kernel<<<2048, 256, 0, stream>>>(
        x, actA, acc, whid, hid_b, wres, res_b, mix_w, in_w, in_b, 0, 1);

    // P1-P3: layers 6,7,8 (d=64,128,256)
    layer_mfma_kernel<<<1024, 256, 0, stream>>>(
        actA, actB, acc, whid + 6 * 16384, hid_b + 6 * 128,
        wres + 6 * 4096, res_b + 6 * 64, mix_w + 6 * 64, 64);
    layer_mfma_kernel<<<1024, 256, 0, stream>>>(
        actB, actA, acc, whid + 7 * 16384, hid_b + 7 * 128,
        wres + 7 * 4096, res_b + 7 * 64, mix_w + 7 * 64, 128);
    layer_mfma_kernel<<<1024, 256, 0, stream>>>(
        actA, actB, acc, whid + 8 * 16384, hid_b + 8 * 128,
        wres + 8 * 4096, res_b + 8 * 64, mix_w + 8 * 64, 256);

    // P4: layers 9-14 (d=1..32) fused -> actA
    fused6_kernel<<<2048, 256, 0, stream>>>(
        actB, actA, acc, whid, hid_b, wres, res_b, mix_w, in_w, in_b, 9, 0);

    // P5-P6: layers 15,16 (d=64,128)
    layer_mfma_kernel<<<1024, 256, 0, stream>>>(
        actA, actB, acc, whid + 15 * 16384, hid_b + 15 * 128,
        wres + 15 * 4096, res_b + 15 * 64, mix_w + 15 * 64, 64);
    layer_mfma_kernel<<<1024, 256, 0, stream>>>(
        actB, actA, acc, whid + 16 * 16384, hid_b + 16 * 128,
        wres + 16 * 4096, res_b + 16 * 64, mix_w + 16 * 64, 128);

    // P7: layer 17 (d=256) + finalize -> out
    last_layer_kernel<<<1024, 256, 0, stream>>>(
        actA, acc, out, whid + 17 * 16384, hid_b + 17 * 128,
        mix_w + 17 * 64, mix_b, 256);
}